// Round 1
// 306.599 us; speedup vs baseline: 1.0401x; 1.0401x over previous
//
#include <hip/hip_runtime.h>

// 2-layer GCN, N=100000, E=1600000, 64 -> 64 -> 1, f32.
//
// Round-5 profile: hist_rank = 77us dominates (VALUBusy 0.9%, HBM 10%,
// WRITE_SIZE 56MB ~= 1.6M x 32B coherent-point atomic traffic). 1.6M
// device-scope 64-bit atomics @ 21 Gops/s = the device-scope atomic rate
// ceiling (they serialize at IF/MALL past the non-coherent per-XCD L2s).
//
// Fix: 8 per-XCD histogram replicas (800KB each, L2-resident). Each block
// reads its XCD via s_getreg(HW_REG_XCC_ID) and uses WORKGROUP-scope
// __hip_atomic_fetch_add -> global_atomic without sc1 -> executes in the
// LOCAL TCC (atomic across the whole XCD; only same-XCD blocks touch a
// replica). Returned old value = rank within (dst,xcd); xcd packed into
// rank[e] high bits. scan1 folds 8 replicas into total cnt + per-xcd
// intra-dst prefix (off8). scatter places at off8[xcd][c]+local_rank.
//
// Workspace overlays (keeps total at 43.2MB < prior 47.2MB):
//   packed8 (6.4MB) overlays pairs   (packed8 dead after scan1)
//   rank    (6.4MB) overlays h1      (gemm1 moved AFTER scatter)
//
// Pipeline:
//   K0 init   : zero packed8[8][N] (6.4MB)
//   K1 hist   : old = xcd-local atomicAdd(packed8[xcd][c], (1<<42)|fix32(w))
//               rank[e] = (xcd<<24) | (old>>42)
//   K2 scan1  : fold 8 replicas -> cnt, dinv, per-xcd prefix -> off8;
//               per-block exclusive scan of cnt -> off, bsum
//   K3 scan2  : scan block sums
//   K4 scan3  : add block offsets to off; off8 += off
//   K5 scatter: pairs[off8[xcd][c]+local_rank] = (r, dinv[r]*w*dinv[c])
//   K6 gemm1  : h1 = x @ W1 (LDS-staged)   [after scatter: h1 overlays rank]
//   K7 gather1: per-dst wave: acc = dinv^2*h1[dst] + sum norm*h1[src]
//               fused relu+b1, dot W2 -> h2[dst]; out[dst] = b2 + h2*dinv^2
//   K8 gather2: per-dst thread: out[dst] += sum norm*h2[src]

#define N_NODES 100000
#define N_EDGES 1600000
#define SCAN_BLOCKS 391   // ceil(100000/256)
#define CNT_SHIFT 42
#define SUM_MASK ((1ull << CNT_SHIFT) - 1)
#define NXCD 8

__global__ void init_zero(ulonglong2* __restrict__ p, int n) {
    int i = blockIdx.x * blockDim.x + threadIdx.x;
    if (i < n) p[i] = make_ulonglong2(0ull, 0ull);
}

// One XCD-local packed 64-bit atomic per edge; returns old -> rank within
// (destination, xcd). Workgroup scope => no sc1 => executes in local TCC.
__global__ void hist_rank(const int* __restrict__ idx, const float* __restrict__ w,
                          unsigned long long* __restrict__ packed8,
                          int* __restrict__ rank, int E) {
    int xcd;
    asm volatile("s_getreg_b32 %0, hwreg(HW_REG_XCC_ID)" : "=s"(xcd));
    xcd &= (NXCD - 1);
    int e = blockIdx.x * blockDim.x + threadIdx.x;
    if (e >= E) return;
    int c = idx[E + e];
    // w in [0,1): w * 2^32 is exact in f32 (power-of-2 scale); trunc error <= 2^-32.
    unsigned long long add =
        (1ull << CNT_SHIFT) | (unsigned long long)(w[e] * 4294967296.0f);
    unsigned long long old = __hip_atomic_fetch_add(
        &packed8[(size_t)xcd * N_NODES + c], add,
        __ATOMIC_RELAXED, __HIP_MEMORY_SCOPE_WORKGROUP);
    rank[e] = (xcd << 24) | (int)(old >> CNT_SHIFT);
}

// Fold 8 replicas -> cnt, dinv, per-xcd intra-dst exclusive prefix (off8);
// per-block exclusive scan of cnt -> off, bsum.
__global__ void scan1(const unsigned long long* __restrict__ packed8,
                      int* __restrict__ cnt, float* __restrict__ dinv,
                      int* __restrict__ off, int* __restrict__ bsum,
                      int* __restrict__ off8, int n) {
    __shared__ int s[256];
    int t = threadIdx.x;
    int i = blockIdx.x * 256 + t;
    int total = 0;
    if (i < n) {
        unsigned long long wsum = 0;
        int pre[NXCD];
#pragma unroll
        for (int x = 0; x < NXCD; x++) {
            unsigned long long p = packed8[(size_t)x * N_NODES + i];
            pre[x] = total;
            total += (int)(p >> CNT_SHIFT);
            wsum += (p & SUM_MASK);
        }
        // deg = 1 (self-loop) + sum(w); fixed-point sum * 2^-32
        float deg = 1.0f + (float)wsum * 2.3283064365386963e-10f;
        dinv[i] = rsqrtf(deg);
        cnt[i] = total;
#pragma unroll
        for (int x = 0; x < NXCD; x++) off8[(size_t)x * N_NODES + i] = pre[x];
    }
    s[t] = total;
    __syncthreads();
#pragma unroll
    for (int d = 1; d < 256; d <<= 1) {
        int u = (t >= d) ? s[t - d] : 0;
        __syncthreads();
        s[t] += u;
        __syncthreads();
    }
    if (i < n) off[i] = s[t] - total;
    if (t == 255) bsum[blockIdx.x] = s[255];
}

// Exclusive scan of block totals (single block, 512 threads >= SCAN_BLOCKS).
__global__ void scan2(int* __restrict__ bsum, int nb) {
    __shared__ int s[512];
    int t = threadIdx.x;
    int v = (t < nb) ? bsum[t] : 0;
    s[t] = v;
    __syncthreads();
#pragma unroll
    for (int d = 1; d < 512; d <<= 1) {
        int u = (t >= d) ? s[t - d] : 0;
        __syncthreads();
        s[t] += u;
        __syncthreads();
    }
    if (t < nb) bsum[t] = s[t] - v;
}

__global__ void scan3(int* __restrict__ off, const int* __restrict__ bsum,
                      int* __restrict__ off8, int n) {
    int i = blockIdx.x * 256 + threadIdx.x;
    if (i < n) {
        int o = off[i] + bsum[blockIdx.x];
        off[i] = o;
#pragma unroll
        for (int x = 0; x < NXCD; x++) off8[(size_t)x * N_NODES + i] += o;
    }
}

// Atomic-free placement using precomputed (xcd, local_rank).
__global__ void scatter(const int* __restrict__ idx, const float* __restrict__ w,
                        const float* __restrict__ dinv, const int* __restrict__ off8,
                        const int* __restrict__ rank, float2* __restrict__ pairs,
                        int E) {
    int e = blockIdx.x * blockDim.x + threadIdx.x;
    if (e >= E) return;
    int r = idx[e];
    int c = idx[E + e];
    float norm = dinv[r] * w[e] * dinv[c];
    int rk = rank[e];
    int pos = off8[(size_t)(rk >> 24) * N_NODES + c] + (rk & 0xFFFFFF);
    pairs[pos] = make_float2(__int_as_float(r), norm);
}

// 16 rows/block; W1 (16KB) + 16 x-rows (4KB) in LDS. Writes h1 only.
__global__ void gemm1(const float* __restrict__ x, const float* __restrict__ W1,
                      float* __restrict__ h1) {
    __shared__ float w1s[64 * 64];
    __shared__ float xs[16 * 64];
    int t = threadIdx.x;
    int row0 = blockIdx.x * 16;

    const float4* W4 = (const float4*)W1;
    float4* w1s4 = (float4*)w1s;
#pragma unroll
    for (int i = 0; i < 4; i++) w1s4[t + 256 * i] = W4[t + 256 * i];
    ((float4*)xs)[t] = ((const float4*)(x + (size_t)row0 * 64))[t];
    __syncthreads();

    int col = t & 63;
    int r0 = t >> 6;
    float acc0 = 0.f, acc1 = 0.f, acc2 = 0.f, acc3 = 0.f;
#pragma unroll
    for (int k = 0; k < 64; k++) {
        float wv = w1s[k * 64 + col];
        acc0 += xs[(r0     ) * 64 + k] * wv;
        acc1 += xs[(r0 +  4) * 64 + k] * wv;
        acc2 += xs[(r0 +  8) * 64 + k] * wv;
        acc3 += xs[(r0 + 12) * 64 + k] * wv;
    }
    float accs[4] = {acc0, acc1, acc2, acc3};
#pragma unroll
    for (int j = 0; j < 4; j++)
        h1[(size_t)(row0 + r0 + 4 * j) * 64 + col] = accs[j];
}

// One wave per dst: 64-channel gather-aggregate, fused relu+b1+W2 projection.
__global__ void gather1(const float* __restrict__ h1, const float2* __restrict__ pairs,
                        const int* __restrict__ off, const int* __restrict__ cnt,
                        const float* __restrict__ dinv, const float* __restrict__ b1,
                        const float* __restrict__ W2, const float* __restrict__ b2,
                        float* __restrict__ h2, float* __restrict__ out, int n) {
    int t = threadIdx.x;
    int lane = t & 63;
    int dst = blockIdx.x * 4 + (t >> 6);
    if (dst >= n) return;
    int beg = off[dst];
    int end = beg + cnt[dst];
    float di = dinv[dst];
    float acc = h1[(size_t)dst * 64 + lane] * di * di;   // self-loop term
    float a0 = 0.f, a1 = 0.f, a2 = 0.f, a3 = 0.f;
    int j = beg;
    for (; j + 4 <= end; j += 4) {
        float2 p0 = pairs[j], p1 = pairs[j + 1], p2 = pairs[j + 2], p3 = pairs[j + 3];
        float v0 = h1[(size_t)__float_as_int(p0.x) * 64 + lane];
        float v1 = h1[(size_t)__float_as_int(p1.x) * 64 + lane];
        float v2 = h1[(size_t)__float_as_int(p2.x) * 64 + lane];
        float v3 = h1[(size_t)__float_as_int(p3.x) * 64 + lane];
        a0 += p0.y * v0; a1 += p1.y * v1; a2 += p2.y * v2; a3 += p3.y * v3;
    }
    for (; j < end; j++) {
        float2 p = pairs[j];
        a0 += p.y * h1[(size_t)__float_as_int(p.x) * 64 + lane];
    }
    acc += (a0 + a1) + (a2 + a3);
    float v = fmaxf(acc + b1[lane], 0.0f);
    float p = v * W2[lane];
#pragma unroll
    for (int offl = 32; offl > 0; offl >>= 1) p += __shfl_xor(p, offl, 64);
    if (lane == 0) {
        h2[dst] = p;
        out[dst] = b2[0] + p * di * di;   // bias + layer-2 self-loop
    }
}

// One thread per dst: out[dst] += sum norm * h2[src].
__global__ void gather2(const float2* __restrict__ pairs, const int* __restrict__ off,
                        const int* __restrict__ cnt, const float* __restrict__ h2,
                        float* __restrict__ out, int n) {
    int i = blockIdx.x * blockDim.x + threadIdx.x;
    if (i >= n) return;
    int beg = off[i];
    int end = beg + cnt[i];
    float s = 0.f;
#pragma unroll 4
    for (int j = beg; j < end; j++) {
        float2 p = pairs[j];
        s += p.y * h2[__float_as_int(p.x)];
    }
    out[i] += s;
}

extern "C" void kernel_launch(void* const* d_in, const int* in_sizes, int n_in,
                              void* d_out, int out_size, void* d_ws, size_t ws_size,
                              hipStream_t stream) {
    const float* x   = (const float*)d_in[0];
    const int*   idx = (const int*)d_in[1];      // int32 per harness contract
    const float* ew  = (const float*)d_in[2];
    const float* W1  = (const float*)d_in[3];
    const float* b1  = (const float*)d_in[4];
    const float* W2  = (const float*)d_in[5];
    const float* b2  = (const float*)d_in[6];
    float* out = (float*)d_out;

    const int N = N_NODES;
    const int E = N_EDGES;

    // ws layout (float units), overlays noted:
    // off[N] | cnt[N] | dinv[N] | bsum[512] | off8[8N] |
    // pairs[2E]  (first 16N floats overlaid by packed8[8N u64])  |
    // h1[64N]    (first E floats overlaid by rank[E])            | h2[N]
    // total = 76N + 512 + 2E = 10,800,512 floats = 43.2 MB
    float* ws = (float*)d_ws;
    int*    off  = (int*)ws;
    int*    cnt  = (int*)(ws + (size_t)N);
    float*  dinv = ws + 2 * (size_t)N;
    int*    bsum = (int*)(ws + 3 * (size_t)N);              // 512 ints
    int*    off8 = (int*)(ws + 3 * (size_t)N + 512);        // 8N ints
    float2* pairs = (float2*)(ws + 11 * (size_t)N + 512);   // 16B-aligned
    unsigned long long* packed8 = (unsigned long long*)pairs;  // overlay (dead after scan1)
    float*  h1 = ws + 11 * (size_t)N + 512 + 2 * (size_t)E; // 16B-aligned
    int*    rank = (int*)h1;                                 // overlay (dead after scatter)
    float*  h2 = h1 + (size_t)N * 64;

    init_zero<<<(4 * N + 255) / 256, 256, 0, stream>>>((ulonglong2*)packed8, 4 * N);
    hist_rank<<<(E + 255) / 256, 256, 0, stream>>>(idx, ew, packed8, rank, E);
    scan1<<<SCAN_BLOCKS, 256, 0, stream>>>(packed8, cnt, dinv, off, bsum, off8, N);
    scan2<<<1, 512, 0, stream>>>(bsum, SCAN_BLOCKS);
    scan3<<<SCAN_BLOCKS, 256, 0, stream>>>(off, bsum, off8, N);
    scatter<<<(E + 255) / 256, 256, 0, stream>>>(idx, ew, dinv, off8, rank, pairs, E);
    gemm1<<<N / 16, 256, 0, stream>>>(x, W1, h1);   // after scatter: h1 overlays rank
    gather1<<<(N + 3) / 4, 256, 0, stream>>>(h1, pairs, off, cnt, dinv, b1, W2, b2, h2, out, N);
    gather2<<<(N + 255) / 256, 256, 0, stream>>>(pairs, off, cnt, h2, out, N);
}

// Round 2
// 288.575 us; speedup vs baseline: 1.1050x; 1.0625x over previous
//
#include <hip/hip_runtime.h>

// 2-layer GCN, N=100000, E=1600000, 64 -> 64 -> 1, f32.
//
// Round-6: global atomics are rate-limited at ~21 Gop/s on gfx950
// (r3: 3.2M ops = 146us, r5: 1.6M ops = 76us; invariant to contention AND
// to workgroup-scope/XCD-replica tricks -- WRITE_SIZE stayed 56MB, each
// returning atomic write-throughs ~32B past L2). So: ZERO global atomics.
// CSR build becomes a two-level LDS counting sort:
//
//   P1  hist  : 512 blocks x 3125 edges; LDS hist over 1563 buckets
//               (bucket = dst>>6); write hist[bucket][block]
//   P2a scan  : per bucket, exclusive scan over 512 block counts (+btot)
//   P2b scan  : exclusive scan of 1563 bucket totals -> boff (+sentinel E)
//   P3  part  : replay edges; LDS-atomic rank in (block,bucket);
//               bin[boff[b]+hist[b][blk]+rank] = (src | clocal<<20, w)
//   P4a count : 1 block/bucket; LDS u64 packed cnt<<42|fix32(wsum) over the
//               bucket's 64 nodes -> cnt[], off[], dinv[] (all nodes covered)
//   P4b place : 1 block/bucket; LDS rank per node; norm = dinv[r]*w*dinv[c];
//               pairs[off[c]+rank] = (src, norm)
//   gemm1     : h1 = x @ W1 (LDS-staged)  [h1 overlays dead hist+bin]
//   gather1   : per-dst wave: acc = dinv^2*h1[dst] + sum norm*h1[src];
//               fused relu+b1, dot W2 -> h2; out = b2 + h2*dinv^2
//   gather2   : per-dst thread: out[dst] += sum norm*h2[src]
//
// All atomics are LDS (ds_add, bank-parallel, ~cycles each). Deterministic
// slot assignment; no init kernel needed.

#define N_NODES 100000
#define N_EDGES 1600000
#define CNT_SHIFT 42
#define SUM_MASK ((1ull << CNT_SHIFT) - 1)
#define NBUCK 1563            // ceil(100000 / 64)
#define NB1 512               // partition blocks
#define EPB 3125              // edges per partition block = E / NB1

// P1: per-block LDS histogram over dst buckets.
__global__ void p1_hist(const int* __restrict__ idx, int* __restrict__ hist) {
    __shared__ int h[NBUCK];
    int t = threadIdx.x, blk = blockIdx.x;
    for (int i = t; i < NBUCK; i += 256) h[i] = 0;
    __syncthreads();
    int e0 = blk * EPB;
    for (int i = t; i < EPB; i += 256) {
        int c = idx[N_EDGES + e0 + i];
        atomicAdd(&h[c >> 6], 1);
    }
    __syncthreads();
    for (int i = t; i < NBUCK; i += 256) hist[(size_t)i * NB1 + blk] = h[i];
}

// P2a: per bucket, exclusive scan of its 512 per-block counts; total -> btot.
__global__ void p2a_scan(int* __restrict__ hist, int* __restrict__ btot) {
    __shared__ int s[NB1];
    int t = threadIdx.x, b = blockIdx.x;
    int v = hist[(size_t)b * NB1 + t];
    s[t] = v;
    __syncthreads();
#pragma unroll
    for (int d = 1; d < NB1; d <<= 1) {
        int u = (t >= d) ? s[t - d] : 0;
        __syncthreads();
        s[t] += u;
        __syncthreads();
    }
    hist[(size_t)b * NB1 + t] = s[t] - v;
    if (t == NB1 - 1) btot[b] = s[NB1 - 1];
}

// P2b: exclusive scan of bucket totals (single block, serial carry).
__global__ void p2b_scan(const int* __restrict__ btot, int* __restrict__ boff) {
    __shared__ int s[256];
    __shared__ int carry;
    int t = threadIdx.x;
    if (t == 0) carry = 0;
    __syncthreads();
    for (int base = 0; base < NBUCK; base += 256) {
        int i = base + t;
        int v = (i < NBUCK) ? btot[i] : 0;
        s[t] = v;
        __syncthreads();
#pragma unroll
        for (int d = 1; d < 256; d <<= 1) {
            int u = (t >= d) ? s[t - d] : 0;
            __syncthreads();
            s[t] += u;
            __syncthreads();
        }
        if (i < NBUCK) boff[i] = carry + s[t] - v;
        __syncthreads();
        if (t == 255) carry += s[255];
        __syncthreads();
    }
    if (t == 0) boff[NBUCK] = carry;   // = E
}

// P3: partition edges into bucket segments (LDS rank, deterministic base).
__global__ void p3_part(const int* __restrict__ idx, const float* __restrict__ w,
                        const int* __restrict__ hist, const int* __restrict__ boff,
                        float2* __restrict__ bin) {
    __shared__ int h[NBUCK];
    int t = threadIdx.x, blk = blockIdx.x;
    for (int i = t; i < NBUCK; i += 256) h[i] = 0;
    __syncthreads();
    int e0 = blk * EPB;
    for (int i = t; i < EPB; i += 256) {
        int e = e0 + i;
        int r = idx[e];
        int c = idx[N_EDGES + e];
        int b = c >> 6;
        int lr = atomicAdd(&h[b], 1);
        int pos = boff[b] + hist[(size_t)b * NB1 + blk] + lr;
        bin[pos] = make_float2(__int_as_float(r | ((c & 63) << 20)), w[e]);
    }
}

// P4a: per bucket, packed per-node count + weight-sum; emit cnt/off/dinv.
__global__ void p4a_count(const float2* __restrict__ bin, const int* __restrict__ boff,
                          int* __restrict__ cnt, int* __restrict__ off,
                          float* __restrict__ dinv) {
    __shared__ unsigned long long pk[64];
    int t = threadIdx.x, b = blockIdx.x;
    if (t < 64) pk[t] = 0ull;
    __syncthreads();
    int s0 = boff[b], s1 = boff[b + 1];
    for (int j = s0 + t; j < s1; j += 256) {
        float2 p = bin[j];
        int cl = (__float_as_int(p.x) >> 20) & 63;
        // w in [0,1): w * 2^32 exact scale; per-node sum < 64*2^32 < 2^42.
        unsigned long long add =
            (1ull << CNT_SHIFT) | (unsigned long long)(p.y * 4294967296.0f);
        atomicAdd(&pk[cl], add);
    }
    __syncthreads();
    if (t < 64) {   // wave 0: scan 64 counters, write per-node outputs
        unsigned long long p = pk[t];
        int c = (int)(p >> CNT_SHIFT);
        int x = c;
#pragma unroll
        for (int d = 1; d < 64; d <<= 1) {
            int u = __shfl_up(x, d, 64);
            if (t >= d) x += u;
        }
        int node = b * 64 + t;
        if (node < N_NODES) {
            off[node] = s0 + x - c;
            cnt[node] = c;
            float deg = 1.0f + (float)(p & SUM_MASK) * 2.3283064365386963e-10f;
            dinv[node] = rsqrtf(deg);
        }
    }
}

// P4b: per bucket, LDS rank per node -> final (src, norm) pairs.
__global__ void p4b_place(const float2* __restrict__ bin, const int* __restrict__ boff,
                          const int* __restrict__ off, const float* __restrict__ dinv,
                          float2* __restrict__ pairs) {
    __shared__ int rk[64];
    int t = threadIdx.x, b = blockIdx.x;
    if (t < 64) rk[t] = 0;
    __syncthreads();
    int s0 = boff[b], s1 = boff[b + 1];
    for (int j = s0 + t; j < s1; j += 256) {
        float2 p = bin[j];
        int bits = __float_as_int(p.x);
        int r = bits & 0xFFFFF;
        int cl = (bits >> 20) & 63;
        int c = (b << 6) + cl;
        int rank = atomicAdd(&rk[cl], 1);
        float norm = dinv[r] * p.y * dinv[c];
        pairs[off[c] + rank] = make_float2(__int_as_float(r), norm);
    }
}

// 16 rows/block; W1 (16KB) + 16 x-rows (4KB) in LDS. Writes h1 only.
__global__ void gemm1(const float* __restrict__ x, const float* __restrict__ W1,
                      float* __restrict__ h1) {
    __shared__ float w1s[64 * 64];
    __shared__ float xs[16 * 64];
    int t = threadIdx.x;
    int row0 = blockIdx.x * 16;

    const float4* W4 = (const float4*)W1;
    float4* w1s4 = (float4*)w1s;
#pragma unroll
    for (int i = 0; i < 4; i++) w1s4[t + 256 * i] = W4[t + 256 * i];
    ((float4*)xs)[t] = ((const float4*)(x + (size_t)row0 * 64))[t];
    __syncthreads();

    int col = t & 63;
    int r0 = t >> 6;
    float acc0 = 0.f, acc1 = 0.f, acc2 = 0.f, acc3 = 0.f;
#pragma unroll
    for (int k = 0; k < 64; k++) {
        float wv = w1s[k * 64 + col];
        acc0 += xs[(r0     ) * 64 + k] * wv;
        acc1 += xs[(r0 +  4) * 64 + k] * wv;
        acc2 += xs[(r0 +  8) * 64 + k] * wv;
        acc3 += xs[(r0 + 12) * 64 + k] * wv;
    }
    float accs[4] = {acc0, acc1, acc2, acc3};
#pragma unroll
    for (int j = 0; j < 4; j++)
        h1[(size_t)(row0 + r0 + 4 * j) * 64 + col] = accs[j];
}

// One wave per dst: 64-channel gather-aggregate, fused relu+b1+W2 projection.
__global__ void gather1(const float* __restrict__ h1, const float2* __restrict__ pairs,
                        const int* __restrict__ off, const int* __restrict__ cnt,
                        const float* __restrict__ dinv, const float* __restrict__ b1,
                        const float* __restrict__ W2, const float* __restrict__ b2,
                        float* __restrict__ h2, float* __restrict__ out, int n) {
    int t = threadIdx.x;
    int lane = t & 63;
    int dst = blockIdx.x * 4 + (t >> 6);
    if (dst >= n) return;
    int beg = off[dst];
    int end = beg + cnt[dst];
    float di = dinv[dst];
    float acc = h1[(size_t)dst * 64 + lane] * di * di;   // self-loop term
    float a0 = 0.f, a1 = 0.f, a2 = 0.f, a3 = 0.f;
    int j = beg;
    for (; j + 4 <= end; j += 4) {
        float2 p0 = pairs[j], p1 = pairs[j + 1], p2 = pairs[j + 2], p3 = pairs[j + 3];
        float v0 = h1[(size_t)__float_as_int(p0.x) * 64 + lane];
        float v1 = h1[(size_t)__float_as_int(p1.x) * 64 + lane];
        float v2 = h1[(size_t)__float_as_int(p2.x) * 64 + lane];
        float v3 = h1[(size_t)__float_as_int(p3.x) * 64 + lane];
        a0 += p0.y * v0; a1 += p1.y * v1; a2 += p2.y * v2; a3 += p3.y * v3;
    }
    for (; j < end; j++) {
        float2 p = pairs[j];
        a0 += p.y * h1[(size_t)__float_as_int(p.x) * 64 + lane];
    }
    acc += (a0 + a1) + (a2 + a3);
    float v = fmaxf(acc + b1[lane], 0.0f);
    float p = v * W2[lane];
#pragma unroll
    for (int offl = 32; offl > 0; offl >>= 1) p += __shfl_xor(p, offl, 64);
    if (lane == 0) {
        h2[dst] = p;
        out[dst] = b2[0] + p * di * di;   // bias + layer-2 self-loop
    }
}

// One thread per dst: out[dst] += sum norm * h2[src].
__global__ void gather2(const float2* __restrict__ pairs, const int* __restrict__ off,
                        const int* __restrict__ cnt, const float* __restrict__ h2,
                        float* __restrict__ out, int n) {
    int i = blockIdx.x * blockDim.x + threadIdx.x;
    if (i >= n) return;
    int beg = off[i];
    int end = beg + cnt[i];
    float s = 0.f;
#pragma unroll 4
    for (int j = beg; j < end; j++) {
        float2 p = pairs[j];
        s += p.y * h2[__float_as_int(p.x)];
    }
    out[i] += s;
}

extern "C" void kernel_launch(void* const* d_in, const int* in_sizes, int n_in,
                              void* d_out, int out_size, void* d_ws, size_t ws_size,
                              hipStream_t stream) {
    const float* x   = (const float*)d_in[0];
    const int*   idx = (const int*)d_in[1];      // int32 per harness contract
    const float* ew  = (const float*)d_in[2];
    const float* W1  = (const float*)d_in[3];
    const float* b1  = (const float*)d_in[4];
    const float* W2  = (const float*)d_in[5];
    const float* b2  = (const float*)d_in[6];
    float* out = (float*)d_out;

    const int N = N_NODES;
    const int E = N_EDGES;

    // ws layout (float units):
    // off[N] | cnt[N] | dinv[N] | boff[NBUCK+1] | btot[NBUCK] | pad |
    // region A (6.4M floats): { hist[NB1*NBUCK]=800256 ints, bin[2E] }
    //                          overlaid later by h1[64N]          |
    // pairs[2E] | h2[N]
    // total = 303128 + 6400000 + 3200000 + 100000 floats = 10,003,128 = 40.0 MB
    float* ws = (float*)d_ws;
    int*    off  = (int*)ws;
    int*    cnt  = (int*)(ws + (size_t)N);
    float*  dinv = ws + 2 * (size_t)N;
    int*    boff = (int*)(ws + 3 * (size_t)N);              // NBUCK+1 = 1564
    int*    btot = (int*)(ws + 3 * (size_t)N + 1564);       // NBUCK
    // region A starts at 303128 (16B aligned)
    int*    hist = (int*)(ws + 303128);                      // 800256 ints
    float2* bin  = (float2*)(ws + 303128 + 800256);          // 2E floats, 8B aligned
    float*  h1   = ws + 303128;                              // overlays hist+bin
    float2* pairs = (float2*)(ws + 303128 + 6400000);        // 2E floats
    float*  h2   = ws + 303128 + 6400000 + 3200000;

    p1_hist<<<NB1, 256, 0, stream>>>(idx, hist);
    p2a_scan<<<NBUCK, NB1, 0, stream>>>(hist, btot);
    p2b_scan<<<1, 256, 0, stream>>>(btot, boff);
    p3_part<<<NB1, 256, 0, stream>>>(idx, ew, hist, boff, bin);
    p4a_count<<<NBUCK, 256, 0, stream>>>(bin, boff, cnt, off, dinv);
    p4b_place<<<NBUCK, 256, 0, stream>>>(bin, boff, off, dinv, pairs);
    gemm1<<<N / 16, 256, 0, stream>>>(x, W1, h1);   // h1 overlays hist+bin (both dead)
    gather1<<<(N + 3) / 4, 256, 0, stream>>>(h1, pairs, off, cnt, dinv, b1, W2, b2, h2, out, N);
    gather2<<<(N + 255) / 256, 256, 0, stream>>>(pairs, off, cnt, h2, out, N);
}

// Round 3
// 273.869 us; speedup vs baseline: 1.1644x; 1.0537x over previous
//
#include <hip/hip_runtime.h>

// 2-layer GCN, N=100000, E=1600000, 64 -> 64 -> 1, f32.
//
// Round-7: CSR build is now atomic-free (two-level LDS counting sort, r6).
// Profile: gather1 = 86us dominates; FETCH_SIZE 275MB = h1-row gathers
// (1.6M x 256B uses of a 25.6MB table; replicated into all 8 per-XCD L2s
// -> >=205MB floor + capacity misses; every byte fetched is used).
// Only lever left: bytes/row. h1 is stored fp16 (128B row, 12.8MB table):
// uses halve to 205MB and L2 hit rate improves. Accumulation + norms stay
// fp32; only the gathered operand is quantized (expected absmax ~2e-3).
//
// Pipeline:
//   P1  hist  : 512 blocks x 3125 edges; LDS hist over 1563 buckets
//               (bucket = dst>>6); write hist[bucket][block]
//   P2a scan  : per bucket, exclusive scan over 512 block counts (+btot)
//   P2b scan  : exclusive scan of 1563 bucket totals -> boff (+sentinel E)
//   P3  part  : replay edges; LDS-atomic rank in (block,bucket);
//               bin[boff[b]+hist[b][blk]+rank] = (src | clocal<<20, w)
//   P4a count : 1 block/bucket; LDS u64 packed cnt<<42|fix32(wsum) over the
//               bucket's 64 nodes -> cnt[], off[], dinv[]
//   P4b place : 1 block/bucket; LDS rank per node; norm = dinv[r]*w*dinv[c];
//               pairs[off[c]+rank] = (src, norm)
//   gemm1     : h1 = fp16(x @ W1) (LDS-staged)  [h1 overlays dead hist+bin]
//   gather1   : per-dst wave: acc = dinv^2*h1[dst] + sum norm*h1[src] (fp32
//               acc of fp16 rows); fused relu+b1, dot W2 -> h2;
//               out = b2 + h2*dinv^2
//   gather2   : per-dst thread: out[dst] += sum norm*h2[src]

#define N_NODES 100000
#define N_EDGES 1600000
#define CNT_SHIFT 42
#define SUM_MASK ((1ull << CNT_SHIFT) - 1)
#define NBUCK 1563            // ceil(100000 / 64)
#define NB1 512               // partition blocks
#define EPB 3125              // edges per partition block = E / NB1

// P1: per-block LDS histogram over dst buckets.
__global__ void p1_hist(const int* __restrict__ idx, int* __restrict__ hist) {
    __shared__ int h[NBUCK];
    int t = threadIdx.x, blk = blockIdx.x;
    for (int i = t; i < NBUCK; i += 256) h[i] = 0;
    __syncthreads();
    int e0 = blk * EPB;
    for (int i = t; i < EPB; i += 256) {
        int c = idx[N_EDGES + e0 + i];
        atomicAdd(&h[c >> 6], 1);
    }
    __syncthreads();
    for (int i = t; i < NBUCK; i += 256) hist[(size_t)i * NB1 + blk] = h[i];
}

// P2a: per bucket, exclusive scan of its 512 per-block counts; total -> btot.
__global__ void p2a_scan(int* __restrict__ hist, int* __restrict__ btot) {
    __shared__ int s[NB1];
    int t = threadIdx.x, b = blockIdx.x;
    int v = hist[(size_t)b * NB1 + t];
    s[t] = v;
    __syncthreads();
#pragma unroll
    for (int d = 1; d < NB1; d <<= 1) {
        int u = (t >= d) ? s[t - d] : 0;
        __syncthreads();
        s[t] += u;
        __syncthreads();
    }
    hist[(size_t)b * NB1 + t] = s[t] - v;
    if (t == NB1 - 1) btot[b] = s[NB1 - 1];
}

// P2b: exclusive scan of bucket totals (single block, serial carry).
__global__ void p2b_scan(const int* __restrict__ btot, int* __restrict__ boff) {
    __shared__ int s[256];
    __shared__ int carry;
    int t = threadIdx.x;
    if (t == 0) carry = 0;
    __syncthreads();
    for (int base = 0; base < NBUCK; base += 256) {
        int i = base + t;
        int v = (i < NBUCK) ? btot[i] : 0;
        s[t] = v;
        __syncthreads();
#pragma unroll
        for (int d = 1; d < 256; d <<= 1) {
            int u = (t >= d) ? s[t - d] : 0;
            __syncthreads();
            s[t] += u;
            __syncthreads();
        }
        if (i < NBUCK) boff[i] = carry + s[t] - v;
        __syncthreads();
        if (t == 255) carry += s[255];
        __syncthreads();
    }
    if (t == 0) boff[NBUCK] = carry;   // = E
}

// P3: partition edges into bucket segments (LDS rank, deterministic base).
__global__ void p3_part(const int* __restrict__ idx, const float* __restrict__ w,
                        const int* __restrict__ hist, const int* __restrict__ boff,
                        float2* __restrict__ bin) {
    __shared__ int h[NBUCK];
    int t = threadIdx.x, blk = blockIdx.x;
    for (int i = t; i < NBUCK; i += 256) h[i] = 0;
    __syncthreads();
    int e0 = blk * EPB;
    for (int i = t; i < EPB; i += 256) {
        int e = e0 + i;
        int r = idx[e];
        int c = idx[N_EDGES + e];
        int b = c >> 6;
        int lr = atomicAdd(&h[b], 1);
        int pos = boff[b] + hist[(size_t)b * NB1 + blk] + lr;
        bin[pos] = make_float2(__int_as_float(r | ((c & 63) << 20)), w[e]);
    }
}

// P4a: per bucket, packed per-node count + weight-sum; emit cnt/off/dinv.
__global__ void p4a_count(const float2* __restrict__ bin, const int* __restrict__ boff,
                          int* __restrict__ cnt, int* __restrict__ off,
                          float* __restrict__ dinv) {
    __shared__ unsigned long long pk[64];
    int t = threadIdx.x, b = blockIdx.x;
    if (t < 64) pk[t] = 0ull;
    __syncthreads();
    int s0 = boff[b], s1 = boff[b + 1];
    for (int j = s0 + t; j < s1; j += 256) {
        float2 p = bin[j];
        int cl = (__float_as_int(p.x) >> 20) & 63;
        // w in [0,1): w * 2^32 exact scale; per-node sum < 64*2^32 < 2^42.
        unsigned long long add =
            (1ull << CNT_SHIFT) | (unsigned long long)(p.y * 4294967296.0f);
        atomicAdd(&pk[cl], add);
    }
    __syncthreads();
    if (t < 64) {   // wave 0: scan 64 counters, write per-node outputs
        unsigned long long p = pk[t];
        int c = (int)(p >> CNT_SHIFT);
        int x = c;
#pragma unroll
        for (int d = 1; d < 64; d <<= 1) {
            int u = __shfl_up(x, d, 64);
            if (t >= d) x += u;
        }
        int node = b * 64 + t;
        if (node < N_NODES) {
            off[node] = s0 + x - c;
            cnt[node] = c;
            float deg = 1.0f + (float)(p & SUM_MASK) * 2.3283064365386963e-10f;
            dinv[node] = rsqrtf(deg);
        }
    }
}

// P4b: per bucket, LDS rank per node -> final (src, norm) pairs.
__global__ void p4b_place(const float2* __restrict__ bin, const int* __restrict__ boff,
                          const int* __restrict__ off, const float* __restrict__ dinv,
                          float2* __restrict__ pairs) {
    __shared__ int rk[64];
    int t = threadIdx.x, b = blockIdx.x;
    if (t < 64) rk[t] = 0;
    __syncthreads();
    int s0 = boff[b], s1 = boff[b + 1];
    for (int j = s0 + t; j < s1; j += 256) {
        float2 p = bin[j];
        int bits = __float_as_int(p.x);
        int r = bits & 0xFFFFF;
        int cl = (bits >> 20) & 63;
        int c = (b << 6) + cl;
        int rank = atomicAdd(&rk[cl], 1);
        float norm = dinv[r] * p.y * dinv[c];
        pairs[off[c] + rank] = make_float2(__int_as_float(r), norm);
    }
}

// 16 rows/block; W1 (16KB) + 16 x-rows (4KB) in LDS. Writes fp16 h1.
__global__ void gemm1(const float* __restrict__ x, const float* __restrict__ W1,
                      _Float16* __restrict__ h1) {
    __shared__ float w1s[64 * 64];
    __shared__ float xs[16 * 64];
    int t = threadIdx.x;
    int row0 = blockIdx.x * 16;

    const float4* W4 = (const float4*)W1;
    float4* w1s4 = (float4*)w1s;
#pragma unroll
    for (int i = 0; i < 4; i++) w1s4[t + 256 * i] = W4[t + 256 * i];
    ((float4*)xs)[t] = ((const float4*)(x + (size_t)row0 * 64))[t];
    __syncthreads();

    int col = t & 63;
    int r0 = t >> 6;
    float acc0 = 0.f, acc1 = 0.f, acc2 = 0.f, acc3 = 0.f;
#pragma unroll
    for (int k = 0; k < 64; k++) {
        float wv = w1s[k * 64 + col];
        acc0 += xs[(r0     ) * 64 + k] * wv;
        acc1 += xs[(r0 +  4) * 64 + k] * wv;
        acc2 += xs[(r0 +  8) * 64 + k] * wv;
        acc3 += xs[(r0 + 12) * 64 + k] * wv;
    }
    float accs[4] = {acc0, acc1, acc2, acc3};
#pragma unroll
    for (int j = 0; j < 4; j++)
        h1[(row0 + r0 + 4 * j) * 64 + col] = (_Float16)accs[j];
}

// One wave per dst: 64-channel fp16-row gather, fp32 accumulate,
// fused relu+b1+W2 projection.
__global__ void gather1(const _Float16* __restrict__ h1, const float2* __restrict__ pairs,
                        const int* __restrict__ off, const int* __restrict__ cnt,
                        const float* __restrict__ dinv, const float* __restrict__ b1,
                        const float* __restrict__ W2, const float* __restrict__ b2,
                        float* __restrict__ h2, float* __restrict__ out, int n) {
    int t = threadIdx.x;
    int lane = t & 63;
    int dst = blockIdx.x * 4 + (t >> 6);
    if (dst >= n) return;
    int beg = off[dst];
    int end = beg + cnt[dst];
    float di = dinv[dst];
    float acc = (float)h1[dst * 64 + lane] * di * di;   // self-loop term
    float a0 = 0.f, a1 = 0.f, a2 = 0.f, a3 = 0.f;
    int j = beg;
    for (; j + 4 <= end; j += 4) {
        float2 p0 = pairs[j], p1 = pairs[j + 1], p2 = pairs[j + 2], p3 = pairs[j + 3];
        float v0 = (float)h1[__float_as_int(p0.x) * 64 + lane];
        float v1 = (float)h1[__float_as_int(p1.x) * 64 + lane];
        float v2 = (float)h1[__float_as_int(p2.x) * 64 + lane];
        float v3 = (float)h1[__float_as_int(p3.x) * 64 + lane];
        a0 += p0.y * v0; a1 += p1.y * v1; a2 += p2.y * v2; a3 += p3.y * v3;
    }
    for (; j < end; j++) {
        float2 p = pairs[j];
        a0 += p.y * (float)h1[__float_as_int(p.x) * 64 + lane];
    }
    acc += (a0 + a1) + (a2 + a3);
    float v = fmaxf(acc + b1[lane], 0.0f);
    float p = v * W2[lane];
#pragma unroll
    for (int offl = 32; offl > 0; offl >>= 1) p += __shfl_xor(p, offl, 64);
    if (lane == 0) {
        h2[dst] = p;
        out[dst] = b2[0] + p * di * di;   // bias + layer-2 self-loop
    }
}

// One thread per dst: out[dst] += sum norm * h2[src].
__global__ void gather2(const float2* __restrict__ pairs, const int* __restrict__ off,
                        const int* __restrict__ cnt, const float* __restrict__ h2,
                        float* __restrict__ out, int n) {
    int i = blockIdx.x * blockDim.x + threadIdx.x;
    if (i >= n) return;
    int beg = off[i];
    int end = beg + cnt[i];
    float s = 0.f;
#pragma unroll 4
    for (int j = beg; j < end; j++) {
        float2 p = pairs[j];
        s += p.y * h2[__float_as_int(p.x)];
    }
    out[i] += s;
}

extern "C" void kernel_launch(void* const* d_in, const int* in_sizes, int n_in,
                              void* d_out, int out_size, void* d_ws, size_t ws_size,
                              hipStream_t stream) {
    const float* x   = (const float*)d_in[0];
    const int*   idx = (const int*)d_in[1];      // int32 per harness contract
    const float* ew  = (const float*)d_in[2];
    const float* W1  = (const float*)d_in[3];
    const float* b1  = (const float*)d_in[4];
    const float* W2  = (const float*)d_in[5];
    const float* b2  = (const float*)d_in[6];
    float* out = (float*)d_out;

    const int N = N_NODES;
    const int E = N_EDGES;

    // ws layout (float units):
    // off[N] | cnt[N] | dinv[N] | boff[NBUCK+1] | btot[NBUCK] | pad |
    // region A (6.4M floats): { hist[NB1*NBUCK]=800256 ints, bin[2E] }
    //                          overlaid later by h1[64N fp16 = 32N floats] |
    // pairs[2E] | h2[N]
    // total = 303128 + 6400000 + 3200000 + 100000 = 10,003,128 floats = 40.0 MB
    float* ws = (float*)d_ws;
    int*    off  = (int*)ws;
    int*    cnt  = (int*)(ws + (size_t)N);
    float*  dinv = ws + 2 * (size_t)N;
    int*    boff = (int*)(ws + 3 * (size_t)N);              // NBUCK+1 = 1564
    int*    btot = (int*)(ws + 3 * (size_t)N + 1564);       // NBUCK
    // region A starts at 303128 (16B aligned)
    int*    hist = (int*)(ws + 303128);                      // 800256 ints
    float2* bin  = (float2*)(ws + 303128 + 800256);          // 2E floats, 8B aligned
    _Float16* h1 = (_Float16*)(ws + 303128);                 // overlays hist+bin
    float2* pairs = (float2*)(ws + 303128 + 6400000);        // 2E floats
    float*  h2   = ws + 303128 + 6400000 + 3200000;

    p1_hist<<<NB1, 256, 0, stream>>>(idx, hist);
    p2a_scan<<<NBUCK, NB1, 0, stream>>>(hist, btot);
    p2b_scan<<<1, 256, 0, stream>>>(btot, boff);
    p3_part<<<NB1, 256, 0, stream>>>(idx, ew, hist, boff, bin);
    p4a_count<<<NBUCK, 256, 0, stream>>>(bin, boff, cnt, off, dinv);
    p4b_place<<<NBUCK, 256, 0, stream>>>(bin, boff, off, dinv, pairs);
    gemm1<<<N / 16, 256, 0, stream>>>(x, W1, h1);   // h1 overlays hist+bin (both dead)
    gather1<<<(N + 3) / 4, 256, 0, stream>>>(h1, pairs, off, cnt, dinv, b1, W2, b2, h2, out, N);
    gather2<<<(N + 255) / 256, 256, 0, stream>>>(pairs, off, cnt, h2, out, N);
}

// Round 4
// 262.816 us; speedup vs baseline: 1.2133x; 1.0421x over previous
//
#include <hip/hip_runtime.h>

// 2-layer GCN, N=100000, E=1600000, 64 -> 64 -> 1, f32.
//
// Round-8: r7's fp16 h1 cut gather1 fetch 275->161MB but BW fell 3.3->2.2TB/s
// (latency-bound: 2B/lane gathers = 128B/instr, only 512B outstanding/wave).
// Fix: gather rows as 32 lanes x dword (2 fp16 ch/lane); the wave's two
// 32-lane halves process even/odd edges concurrently -> 8 edges (1KB) in
// flight per wave, half the gather instructions. fp32 accumulate; one
// shfl_xor(32) merges halves, then relu+b1, 2-ch W2 dot, 32-lane reduce.
//
// Pipeline (CSR build = two-level LDS counting sort, zero global atomics):
//   P1  hist  : 512 blocks x 3125 edges; LDS hist over 1563 buckets
//   P2a scan  : per bucket, exclusive scan over 512 block counts (+btot)
//   P2b scan  : exclusive scan of 1563 bucket totals -> boff (+sentinel E)
//   P3  part  : replay edges; LDS rank in (block,bucket); bin = (src|cl<<20, w)
//   P4a count : 1 block/bucket; packed u64 cnt/wsum -> cnt[], off[], dinv[]
//   P4b place : 1 block/bucket; LDS rank; pairs[off[c]+rank] = (src, norm)
//   gemm1     : h1 = fp16(x @ W1)   [h1 overlays dead hist+bin]
//   gather1   : per-dst wave (split-half dword gather), fused relu+b1+W2
//   gather2   : per-dst thread: out[dst] += sum norm*h2[src]

#define N_NODES 100000
#define N_EDGES 1600000
#define CNT_SHIFT 42
#define SUM_MASK ((1ull << CNT_SHIFT) - 1)
#define NBUCK 1563            // ceil(100000 / 64)
#define NB1 512               // partition blocks
#define EPB 3125              // edges per partition block = E / NB1

typedef _Float16 half2v __attribute__((ext_vector_type(2)));

// P1: per-block LDS histogram over dst buckets.
__global__ void p1_hist(const int* __restrict__ idx, int* __restrict__ hist) {
    __shared__ int h[NBUCK];
    int t = threadIdx.x, blk = blockIdx.x;
    for (int i = t; i < NBUCK; i += 256) h[i] = 0;
    __syncthreads();
    int e0 = blk * EPB;
    for (int i = t; i < EPB; i += 256) {
        int c = idx[N_EDGES + e0 + i];
        atomicAdd(&h[c >> 6], 1);
    }
    __syncthreads();
    for (int i = t; i < NBUCK; i += 256) hist[(size_t)i * NB1 + blk] = h[i];
}

// P2a: per bucket, exclusive scan of its 512 per-block counts; total -> btot.
__global__ void p2a_scan(int* __restrict__ hist, int* __restrict__ btot) {
    __shared__ int s[NB1];
    int t = threadIdx.x, b = blockIdx.x;
    int v = hist[(size_t)b * NB1 + t];
    s[t] = v;
    __syncthreads();
#pragma unroll
    for (int d = 1; d < NB1; d <<= 1) {
        int u = (t >= d) ? s[t - d] : 0;
        __syncthreads();
        s[t] += u;
        __syncthreads();
    }
    hist[(size_t)b * NB1 + t] = s[t] - v;
    if (t == NB1 - 1) btot[b] = s[NB1 - 1];
}

// P2b: exclusive scan of bucket totals (single block, serial carry).
__global__ void p2b_scan(const int* __restrict__ btot, int* __restrict__ boff) {
    __shared__ int s[256];
    __shared__ int carry;
    int t = threadIdx.x;
    if (t == 0) carry = 0;
    __syncthreads();
    for (int base = 0; base < NBUCK; base += 256) {
        int i = base + t;
        int v = (i < NBUCK) ? btot[i] : 0;
        s[t] = v;
        __syncthreads();
#pragma unroll
        for (int d = 1; d < 256; d <<= 1) {
            int u = (t >= d) ? s[t - d] : 0;
            __syncthreads();
            s[t] += u;
            __syncthreads();
        }
        if (i < NBUCK) boff[i] = carry + s[t] - v;
        __syncthreads();
        if (t == 255) carry += s[255];
        __syncthreads();
    }
    if (t == 0) boff[NBUCK] = carry;   // = E
}

// P3: partition edges into bucket segments (LDS rank, deterministic base).
__global__ void p3_part(const int* __restrict__ idx, const float* __restrict__ w,
                        const int* __restrict__ hist, const int* __restrict__ boff,
                        float2* __restrict__ bin) {
    __shared__ int h[NBUCK];
    int t = threadIdx.x, blk = blockIdx.x;
    for (int i = t; i < NBUCK; i += 256) h[i] = 0;
    __syncthreads();
    int e0 = blk * EPB;
    for (int i = t; i < EPB; i += 256) {
        int e = e0 + i;
        int r = idx[e];
        int c = idx[N_EDGES + e];
        int b = c >> 6;
        int lr = atomicAdd(&h[b], 1);
        int pos = boff[b] + hist[(size_t)b * NB1 + blk] + lr;
        bin[pos] = make_float2(__int_as_float(r | ((c & 63) << 20)), w[e]);
    }
}

// P4a: per bucket, packed per-node count + weight-sum; emit cnt/off/dinv.
__global__ void p4a_count(const float2* __restrict__ bin, const int* __restrict__ boff,
                          int* __restrict__ cnt, int* __restrict__ off,
                          float* __restrict__ dinv) {
    __shared__ unsigned long long pk[64];
    int t = threadIdx.x, b = blockIdx.x;
    if (t < 64) pk[t] = 0ull;
    __syncthreads();
    int s0 = boff[b], s1 = boff[b + 1];
    for (int j = s0 + t; j < s1; j += 256) {
        float2 p = bin[j];
        int cl = (__float_as_int(p.x) >> 20) & 63;
        // w in [0,1): w * 2^32 exact scale; per-node sum < 64*2^32 < 2^42.
        unsigned long long add =
            (1ull << CNT_SHIFT) | (unsigned long long)(p.y * 4294967296.0f);
        atomicAdd(&pk[cl], add);
    }
    __syncthreads();
    if (t < 64) {   // wave 0: scan 64 counters, write per-node outputs
        unsigned long long p = pk[t];
        int c = (int)(p >> CNT_SHIFT);
        int x = c;
#pragma unroll
        for (int d = 1; d < 64; d <<= 1) {
            int u = __shfl_up(x, d, 64);
            if (t >= d) x += u;
        }
        int node = b * 64 + t;
        if (node < N_NODES) {
            off[node] = s0 + x - c;
            cnt[node] = c;
            float deg = 1.0f + (float)(p & SUM_MASK) * 2.3283064365386963e-10f;
            dinv[node] = rsqrtf(deg);
        }
    }
}

// P4b: per bucket, LDS rank per node -> final (src, norm) pairs.
__global__ void p4b_place(const float2* __restrict__ bin, const int* __restrict__ boff,
                          const int* __restrict__ off, const float* __restrict__ dinv,
                          float2* __restrict__ pairs) {
    __shared__ int rk[64];
    int t = threadIdx.x, b = blockIdx.x;
    if (t < 64) rk[t] = 0;
    __syncthreads();
    int s0 = boff[b], s1 = boff[b + 1];
    for (int j = s0 + t; j < s1; j += 256) {
        float2 p = bin[j];
        int bits = __float_as_int(p.x);
        int r = bits & 0xFFFFF;
        int cl = (bits >> 20) & 63;
        int c = (b << 6) + cl;
        int rank = atomicAdd(&rk[cl], 1);
        float norm = dinv[r] * p.y * dinv[c];
        pairs[off[c] + rank] = make_float2(__int_as_float(r), norm);
    }
}

// 16 rows/block; W1 (16KB) + 16 x-rows (4KB) in LDS. Writes fp16 h1.
__global__ void gemm1(const float* __restrict__ x, const float* __restrict__ W1,
                      _Float16* __restrict__ h1) {
    __shared__ float w1s[64 * 64];
    __shared__ float xs[16 * 64];
    int t = threadIdx.x;
    int row0 = blockIdx.x * 16;

    const float4* W4 = (const float4*)W1;
    float4* w1s4 = (float4*)w1s;
#pragma unroll
    for (int i = 0; i < 4; i++) w1s4[t + 256 * i] = W4[t + 256 * i];
    ((float4*)xs)[t] = ((const float4*)(x + (size_t)row0 * 64))[t];
    __syncthreads();

    int col = t & 63;
    int r0 = t >> 6;
    float acc0 = 0.f, acc1 = 0.f, acc2 = 0.f, acc3 = 0.f;
#pragma unroll
    for (int k = 0; k < 64; k++) {
        float wv = w1s[k * 64 + col];
        acc0 += xs[(r0     ) * 64 + k] * wv;
        acc1 += xs[(r0 +  4) * 64 + k] * wv;
        acc2 += xs[(r0 +  8) * 64 + k] * wv;
        acc3 += xs[(r0 + 12) * 64 + k] * wv;
    }
    float accs[4] = {acc0, acc1, acc2, acc3};
#pragma unroll
    for (int j = 0; j < 4; j++)
        h1[(row0 + r0 + 4 * j) * 64 + col] = (_Float16)accs[j];
}

// One wave per dst. Row gathers are 32 lanes x dword (2 fp16 ch/lane);
// lane halves (lane<32 / lane>=32) process even/odd edges concurrently:
// 8 edges (1KB) in flight per wave iteration. fp32 accumulate; one
// shfl_xor(32) merges halves; fused relu+b1 + 2-ch W2 dot + 32-lane reduce.
__global__ void gather1(const half2v* __restrict__ h1v, const float2* __restrict__ pairs,
                        const int* __restrict__ off, const int* __restrict__ cnt,
                        const float* __restrict__ dinv, const float* __restrict__ b1,
                        const float* __restrict__ W2, const float* __restrict__ b2,
                        float* __restrict__ h2, float* __restrict__ out, int n) {
    int t = threadIdx.x;
    int lane = t & 63;
    int half = lane >> 5;       // 0: even edges, 1: odd edges
    int cl = lane & 31;         // channel pair: handles ch 2*cl, 2*cl+1
    int dst = blockIdx.x * 4 + (t >> 6);
    if (dst >= n) return;
    int beg = off[dst];
    int end = beg + cnt[dst];
    float di = dinv[dst];
    float a0 = 0.f, a1 = 0.f, b0 = 0.f, b1a = 0.f;
    float c0 = 0.f, c1 = 0.f, d0 = 0.f, d1 = 0.f;
    int j = beg + half;
    for (; j + 6 < end; j += 8) {   // 4 edges per half per iter
        float2 p0 = pairs[j], p1 = pairs[j + 2], p2 = pairs[j + 4], p3 = pairs[j + 6];
        half2v v0 = h1v[__float_as_int(p0.x) * 32 + cl];
        half2v v1 = h1v[__float_as_int(p1.x) * 32 + cl];
        half2v v2 = h1v[__float_as_int(p2.x) * 32 + cl];
        half2v v3 = h1v[__float_as_int(p3.x) * 32 + cl];
        a0 += p0.y * (float)v0[0]; a1 += p0.y * (float)v0[1];
        b0 += p1.y * (float)v1[0]; b1a += p1.y * (float)v1[1];
        c0 += p2.y * (float)v2[0]; c1 += p2.y * (float)v2[1];
        d0 += p3.y * (float)v3[0]; d1 += p3.y * (float)v3[1];
    }
    for (; j < end; j += 2) {
        float2 p = pairs[j];
        half2v v = h1v[__float_as_int(p.x) * 32 + cl];
        a0 += p.y * (float)v[0]; a1 += p.y * (float)v[1];
    }
    float t0 = (a0 + b0) + (c0 + d0);
    float t1 = (a1 + b1a) + (c1 + d1);
    // merge even/odd halves (lanes l and l^32 hold same channels)
    t0 += __shfl_xor(t0, 32, 64);
    t1 += __shfl_xor(t1, 32, 64);
    // self-loop term (after merge so it's added once)
    half2v sv = h1v[dst * 32 + cl];
    t0 += (float)sv[0] * di * di;
    t1 += (float)sv[1] * di * di;
    float2 b1p = ((const float2*)b1)[cl];
    float v0 = fmaxf(t0 + b1p.x, 0.0f);
    float v1 = fmaxf(t1 + b1p.y, 0.0f);
    float2 w2p = ((const float2*)W2)[cl];
    float p = v0 * w2p.x + v1 * w2p.y;
#pragma unroll
    for (int o = 16; o > 0; o >>= 1) p += __shfl_xor(p, o, 64);
    // lanes 0 and 32 hold identical totals; lane 0 writes
    if (lane == 0) {
        h2[dst] = p;
        out[dst] = b2[0] + p * di * di;   // bias + layer-2 self-loop
    }
}

// One thread per dst: out[dst] += sum norm * h2[src].
__global__ void gather2(const float2* __restrict__ pairs, const int* __restrict__ off,
                        const int* __restrict__ cnt, const float* __restrict__ h2,
                        float* __restrict__ out, int n) {
    int i = blockIdx.x * blockDim.x + threadIdx.x;
    if (i >= n) return;
    int beg = off[i];
    int end = beg + cnt[i];
    float s = 0.f;
#pragma unroll 4
    for (int j = beg; j < end; j++) {
        float2 p = pairs[j];
        s += p.y * h2[__float_as_int(p.x)];
    }
    out[i] += s;
}

extern "C" void kernel_launch(void* const* d_in, const int* in_sizes, int n_in,
                              void* d_out, int out_size, void* d_ws, size_t ws_size,
                              hipStream_t stream) {
    const float* x   = (const float*)d_in[0];
    const int*   idx = (const int*)d_in[1];      // int32 per harness contract
    const float* ew  = (const float*)d_in[2];
    const float* W1  = (const float*)d_in[3];
    const float* b1  = (const float*)d_in[4];
    const float* W2  = (const float*)d_in[5];
    const float* b2  = (const float*)d_in[6];
    float* out = (float*)d_out;

    const int N = N_NODES;
    const int E = N_EDGES;

    // ws layout (float units):
    // off[N] | cnt[N] | dinv[N] | boff[NBUCK+1] | btot[NBUCK] | pad |
    // region A (6.4M floats): { hist[NB1*NBUCK]=800256 ints, bin[2E] }
    //                          overlaid later by h1[64N fp16 = 32N floats] |
    // pairs[2E] | h2[N]
    // total = 303128 + 6400000 + 3200000 + 100000 = 10,003,128 floats = 40.0 MB
    float* ws = (float*)d_ws;
    int*    off  = (int*)ws;
    int*    cnt  = (int*)(ws + (size_t)N);
    float*  dinv = ws + 2 * (size_t)N;
    int*    boff = (int*)(ws + 3 * (size_t)N);              // NBUCK+1 = 1564
    int*    btot = (int*)(ws + 3 * (size_t)N + 1564);       // NBUCK
    // region A starts at 303128 (16B aligned)
    int*    hist = (int*)(ws + 303128);                      // 800256 ints
    float2* bin  = (float2*)(ws + 303128 + 800256);          // 2E floats, 8B aligned
    _Float16* h1 = (_Float16*)(ws + 303128);                 // overlays hist+bin
    float2* pairs = (float2*)(ws + 303128 + 6400000);        // 2E floats
    float*  h2   = ws + 303128 + 6400000 + 3200000;

    p1_hist<<<NB1, 256, 0, stream>>>(idx, hist);
    p2a_scan<<<NBUCK, NB1, 0, stream>>>(hist, btot);
    p2b_scan<<<1, 256, 0, stream>>>(btot, boff);
    p3_part<<<NB1, 256, 0, stream>>>(idx, ew, hist, boff, bin);
    p4a_count<<<NBUCK, 256, 0, stream>>>(bin, boff, cnt, off, dinv);
    p4b_place<<<NBUCK, 256, 0, stream>>>(bin, boff, off, dinv, pairs);
    gemm1<<<N / 16, 256, 0, stream>>>(x, W1, h1);   // h1 overlays hist+bin (both dead)
    gather1<<<(N + 3) / 4, 256, 0, stream>>>((const half2v*)h1, pairs, off, cnt, dinv,
                                             b1, W2, b2, h2, out, N);
    gather2<<<(N + 255) / 256, 256, 0, stream>>>(pairs, off, cnt, h2, out, N);
}

// Round 5
// 228.355 us; speedup vs baseline: 1.3964x; 1.1509x over previous
//
#include <hip/hip_runtime.h>

// 2-layer GCN, N=100000, E=1600000, 64 -> 64 -> 1, f32.
//
// Round-9. r8 post-mortem: gather1 65us (fetch 161MB, 2.55TB/s) - still
// latency-bound; other 8 kernels sum ~197us. This round:
//  1) bucket 64->256 nodes (NBUCK=391): p3 bin-write runs grow 16B->64B
//     (kills partial-line RFO amplification); p1 LDS hist + p2a shrink 4x.
//  2) gather1: 8 edges/half in flight (2KB/wave) + 128-thread blocks.
//  3) gemm1: 64 rows/block, 4x4 outputs/thread, ds_read_b128 W-quad:
//     16 FMA per 5 LDS ops (was 4 per 5).
//
// Pipeline (CSR build = two-level LDS counting sort, zero global atomics):
//   P1  hist  : 512 blocks x 3125 edges; LDS hist over 391 buckets
//   P2a scan  : per bucket, exclusive scan over 512 block counts (+btot)
//   P2b scan  : exclusive scan of 391 bucket totals -> boff (+sentinel E)
//   P3  part  : replay edges; LDS rank in (block,bucket); bin=(src|cl<<17, w)
//   P4a count : 1 block/bucket; packed u64 cnt/wsum + 256-scan -> cnt/off/dinv
//   P4b place : 1 block/bucket; LDS rank; pairs[off[c]+rank] = (src, norm)
//   gemm1     : h1 = fp16(x @ W1)   [h1 overlays dead hist+bin]
//   gather1   : per-dst wave (split-half dword gather, 8-deep), relu+b1+W2
//   gather2   : per-dst thread: out[dst] += sum norm*h2[src]

#define N_NODES 100000
#define N_EDGES 1600000
#define CNT_SHIFT 42
#define SUM_MASK ((1ull << CNT_SHIFT) - 1)
#define BSZ 256               // nodes per bucket
#define NBUCK 391             // ceil(100000 / 256)
#define NB1 512               // partition blocks
#define EPB 3125              // edges per partition block = E / NB1

typedef _Float16 half2v __attribute__((ext_vector_type(2)));

// P1: per-block LDS histogram over dst buckets.
__global__ void p1_hist(const int* __restrict__ idx, int* __restrict__ hist) {
    __shared__ int h[NBUCK];
    int t = threadIdx.x, blk = blockIdx.x;
    for (int i = t; i < NBUCK; i += 256) h[i] = 0;
    __syncthreads();
    int e0 = blk * EPB;
    for (int i = t; i < EPB; i += 256) {
        int c = idx[N_EDGES + e0 + i];
        atomicAdd(&h[c >> 8], 1);
    }
    __syncthreads();
    for (int i = t; i < NBUCK; i += 256) hist[(size_t)i * NB1 + blk] = h[i];
}

// P2a: per bucket, exclusive scan of its 512 per-block counts; total -> btot.
__global__ void p2a_scan(int* __restrict__ hist, int* __restrict__ btot) {
    __shared__ int s[NB1];
    int t = threadIdx.x, b = blockIdx.x;
    int v = hist[(size_t)b * NB1 + t];
    s[t] = v;
    __syncthreads();
#pragma unroll
    for (int d = 1; d < NB1; d <<= 1) {
        int u = (t >= d) ? s[t - d] : 0;
        __syncthreads();
        s[t] += u;
        __syncthreads();
    }
    hist[(size_t)b * NB1 + t] = s[t] - v;
    if (t == NB1 - 1) btot[b] = s[NB1 - 1];
}

// P2b: exclusive scan of 391 bucket totals (single 512-thread block).
__global__ void p2b_scan(const int* __restrict__ btot, int* __restrict__ boff) {
    __shared__ int s[512];
    int t = threadIdx.x;
    int v = (t < NBUCK) ? btot[t] : 0;
    s[t] = v;
    __syncthreads();
#pragma unroll
    for (int d = 1; d < 512; d <<= 1) {
        int u = (t >= d) ? s[t - d] : 0;
        __syncthreads();
        s[t] += u;
        __syncthreads();
    }
    if (t < NBUCK) boff[t] = s[t] - v;
    if (t == 511) boff[NBUCK] = s[511];   // = E
}

// P3: partition edges into bucket segments (LDS rank, deterministic base).
__global__ void p3_part(const int* __restrict__ idx, const float* __restrict__ w,
                        const int* __restrict__ hist, const int* __restrict__ boff,
                        float2* __restrict__ bin) {
    __shared__ int h[NBUCK];
    __shared__ int base[NBUCK];
    int t = threadIdx.x, blk = blockIdx.x;
    for (int i = t; i < NBUCK; i += 256) {
        h[i] = 0;
        base[i] = boff[i] + hist[(size_t)i * NB1 + blk];
    }
    __syncthreads();
    int e0 = blk * EPB;
    for (int i = t; i < EPB; i += 256) {
        int e = e0 + i;
        int r = idx[e];
        int c = idx[N_EDGES + e];
        int b = c >> 8;
        int lr = atomicAdd(&h[b], 1);
        bin[base[b] + lr] = make_float2(__int_as_float(r | ((c & 255) << 17)), w[e]);
    }
}

// P4a: per bucket, packed per-node count + weight-sum; 256-scan -> cnt/off/dinv.
__global__ void p4a_count(const float2* __restrict__ bin, const int* __restrict__ boff,
                          int* __restrict__ cnt, int* __restrict__ off,
                          float* __restrict__ dinv) {
    __shared__ unsigned long long pk[BSZ];
    __shared__ int s[BSZ];
    int t = threadIdx.x, b = blockIdx.x;
    if (t < BSZ) pk[t] = 0ull;
    __syncthreads();
    int s0 = boff[b], s1 = boff[b + 1];
    for (int j = s0 + t; j < s1; j += 512) {
        float2 p = bin[j];
        int cl = (__float_as_int(p.x) >> 17) & 255;
        // w in [0,1): w * 2^32 exact scale; per-node sum < cnt*2^32 < 2^42.
        unsigned long long add =
            (1ull << CNT_SHIFT) | (unsigned long long)(p.y * 4294967296.0f);
        atomicAdd(&pk[cl], add);
    }
    __syncthreads();
    unsigned long long p = 0;
    int c = 0;
    if (t < BSZ) {
        p = pk[t];
        c = (int)(p >> CNT_SHIFT);
        s[t] = c;
    }
    __syncthreads();
#pragma unroll
    for (int d = 1; d < BSZ; d <<= 1) {
        int u = (t >= d && t < BSZ) ? s[t - d] : 0;
        __syncthreads();
        if (t < BSZ) s[t] += u;
        __syncthreads();
    }
    if (t < BSZ) {
        int node = b * BSZ + t;
        if (node < N_NODES) {
            off[node] = s0 + s[t] - c;
            cnt[node] = c;
            float deg = 1.0f + (float)(p & SUM_MASK) * 2.3283064365386963e-10f;
            dinv[node] = rsqrtf(deg);
        }
    }
}

// P4b: per bucket, LDS rank per node -> final (src, norm) pairs.
__global__ void p4b_place(const float2* __restrict__ bin, const int* __restrict__ boff,
                          const int* __restrict__ off, const float* __restrict__ dinv,
                          float2* __restrict__ pairs) {
    __shared__ int rk[BSZ];
    int t = threadIdx.x, b = blockIdx.x;
    if (t < BSZ) rk[t] = 0;
    __syncthreads();
    int s0 = boff[b], s1 = boff[b + 1];
    for (int j = s0 + t; j < s1; j += 512) {
        float2 p = bin[j];
        int bits = __float_as_int(p.x);
        int r = bits & 0x1FFFF;
        int cl = (bits >> 17) & 255;
        int c = (b << 8) + cl;
        int rank = atomicAdd(&rk[cl], 1);
        float norm = dinv[r] * p.y * dinv[c];
        pairs[off[c] + rank] = make_float2(__int_as_float(r), norm);
    }
}

// 64 rows/block; each thread computes 4 rows x 4 cols: 16 FMA per
// (1 ds_read_b128 + 4 broadcast ds_read_b32). Writes fp16 h1.
__global__ void gemm1(const float* __restrict__ x, const float* __restrict__ W1,
                      _Float16* __restrict__ h1) {
    __shared__ float w1s[64 * 64];
    __shared__ float xs[64 * 64];
    int t = threadIdx.x;
    int row0 = blockIdx.x * 64;

    const float4* W4 = (const float4*)W1;
    float4* w1s4 = (float4*)w1s;
    float4* xs4 = (float4*)xs;
    const float4* X4 = (const float4*)(x + (size_t)row0 * 64);
#pragma unroll
    for (int i = 0; i < 4; i++) {
        w1s4[t + 256 * i] = W4[t + 256 * i];
        int gr = row0 + ((t + 256 * i) >> 4);
        xs4[t + 256 * i] = (gr < N_NODES) ? X4[t + 256 * i]
                                          : make_float4(0.f, 0.f, 0.f, 0.f);
    }
    __syncthreads();

    int cq = t & 15;    // cols 4cq..4cq+3
    int rq = t >> 4;    // rows rq, rq+16, rq+32, rq+48
    float4 acc0 = {0,0,0,0}, acc1 = {0,0,0,0}, acc2 = {0,0,0,0}, acc3 = {0,0,0,0};
#pragma unroll 4
    for (int k = 0; k < 64; k++) {
        float4 wv = w1s4[k * 16 + cq];
        float x0 = xs[(rq     ) * 64 + k];
        float x1 = xs[(rq + 16) * 64 + k];
        float x2 = xs[(rq + 32) * 64 + k];
        float x3 = xs[(rq + 48) * 64 + k];
        acc0.x += x0*wv.x; acc0.y += x0*wv.y; acc0.z += x0*wv.z; acc0.w += x0*wv.w;
        acc1.x += x1*wv.x; acc1.y += x1*wv.y; acc1.z += x1*wv.z; acc1.w += x1*wv.w;
        acc2.x += x2*wv.x; acc2.y += x2*wv.y; acc2.z += x2*wv.z; acc2.w += x2*wv.w;
        acc3.x += x3*wv.x; acc3.y += x3*wv.y; acc3.z += x3*wv.z; acc3.w += x3*wv.w;
    }
    float4 accs[4] = {acc0, acc1, acc2, acc3};
#pragma unroll
    for (int i = 0; i < 4; i++) {
        int row = row0 + rq + 16 * i;
        if (row < N_NODES) {
            half2v h01 = {(_Float16)accs[i].x, (_Float16)accs[i].y};
            half2v h23 = {(_Float16)accs[i].z, (_Float16)accs[i].w};
            half2v* dst = (half2v*)(h1 + (size_t)row * 64 + 4 * cq);
            dst[0] = h01;
            dst[1] = h23;
        }
    }
}

// One wave per dst. Rows gathered as 32 lanes x dword (2 fp16 ch/lane);
// halves process even/odd edges, 8 edges per half in flight (2KB/wave).
// 128-thread blocks (2 dsts) for finer scheduling granularity.
__global__ void gather1(const half2v* __restrict__ h1v, const float2* __restrict__ pairs,
                        const int* __restrict__ off, const int* __restrict__ cnt,
                        const float* __restrict__ dinv, const float* __restrict__ b1,
                        const float* __restrict__ W2, const float* __restrict__ b2,
                        float* __restrict__ h2, float* __restrict__ out, int n) {
    int t = threadIdx.x;
    int lane = t & 63;
    int half = lane >> 5;       // 0: even edges, 1: odd edges
    int cl = lane & 31;         // channel pair: handles ch 2*cl, 2*cl+1
    int dst = blockIdx.x * 2 + (t >> 6);
    if (dst >= n) return;
    int beg = off[dst];
    int end = beg + cnt[dst];
    float di = dinv[dst];
    float a0 = 0.f, a1 = 0.f, b0 = 0.f, b1a = 0.f;
    float c0 = 0.f, c1 = 0.f, d0 = 0.f, d1 = 0.f;
    int j = beg + half;
    for (; j + 14 < end; j += 16) {   // 8 edges per half per iter
        float2 p0 = pairs[j],      p1 = pairs[j + 2],  p2 = pairs[j + 4],  p3 = pairs[j + 6];
        float2 p4 = pairs[j + 8],  p5 = pairs[j + 10], p6 = pairs[j + 12], p7 = pairs[j + 14];
        half2v v0 = h1v[__float_as_int(p0.x) * 32 + cl];
        half2v v1 = h1v[__float_as_int(p1.x) * 32 + cl];
        half2v v2 = h1v[__float_as_int(p2.x) * 32 + cl];
        half2v v3 = h1v[__float_as_int(p3.x) * 32 + cl];
        half2v v4 = h1v[__float_as_int(p4.x) * 32 + cl];
        half2v v5 = h1v[__float_as_int(p5.x) * 32 + cl];
        half2v v6 = h1v[__float_as_int(p6.x) * 32 + cl];
        half2v v7 = h1v[__float_as_int(p7.x) * 32 + cl];
        a0 += p0.y * (float)v0[0]; a1 += p0.y * (float)v0[1];
        b0 += p1.y * (float)v1[0]; b1a += p1.y * (float)v1[1];
        c0 += p2.y * (float)v2[0]; c1 += p2.y * (float)v2[1];
        d0 += p3.y * (float)v3[0]; d1 += p3.y * (float)v3[1];
        a0 += p4.y * (float)v4[0]; a1 += p4.y * (float)v4[1];
        b0 += p5.y * (float)v5[0]; b1a += p5.y * (float)v5[1];
        c0 += p6.y * (float)v6[0]; c1 += p6.y * (float)v6[1];
        d0 += p7.y * (float)v7[0]; d1 += p7.y * (float)v7[1];
    }
    for (; j + 6 < end; j += 8) {     // 4 edges per half
        float2 p0 = pairs[j], p1 = pairs[j + 2], p2 = pairs[j + 4], p3 = pairs[j + 6];
        half2v v0 = h1v[__float_as_int(p0.x) * 32 + cl];
        half2v v1 = h1v[__float_as_int(p1.x) * 32 + cl];
        half2v v2 = h1v[__float_as_int(p2.x) * 32 + cl];
        half2v v3 = h1v[__float_as_int(p3.x) * 32 + cl];
        a0 += p0.y * (float)v0[0]; a1 += p0.y * (float)v0[1];
        b0 += p1.y * (float)v1[0]; b1a += p1.y * (float)v1[1];
        c0 += p2.y * (float)v2[0]; c1 += p2.y * (float)v2[1];
        d0 += p3.y * (float)v3[0]; d1 += p3.y * (float)v3[1];
    }
    for (; j < end; j += 2) {
        float2 p = pairs[j];
        half2v v = h1v[__float_as_int(p.x) * 32 + cl];
        a0 += p.y * (float)v[0]; a1 += p.y * (float)v[1];
    }
    float t0 = (a0 + b0) + (c0 + d0);
    float t1 = (a1 + b1a) + (c1 + d1);
    // merge even/odd halves (lanes l and l^32 hold same channels)
    t0 += __shfl_xor(t0, 32, 64);
    t1 += __shfl_xor(t1, 32, 64);
    // self-loop term (after merge so it's added once)
    half2v sv = h1v[dst * 32 + cl];
    t0 += (float)sv[0] * di * di;
    t1 += (float)sv[1] * di * di;
    float2 b1p = ((const float2*)b1)[cl];
    float v0 = fmaxf(t0 + b1p.x, 0.0f);
    float v1 = fmaxf(t1 + b1p.y, 0.0f);
    float2 w2p = ((const float2*)W2)[cl];
    float p = v0 * w2p.x + v1 * w2p.y;
#pragma unroll
    for (int o = 16; o > 0; o >>= 1) p += __shfl_xor(p, o, 64);
    // lanes 0 and 32 hold identical totals; lane 0 writes
    if (lane == 0) {
        h2[dst] = p;
        out[dst] = b2[0] + p * di * di;   // bias + layer-2 self-loop
    }
}

// One thread per dst: out[dst] += sum norm * h2[src].
__global__ void gather2(const float2* __restrict__ pairs, const int* __restrict__ off,
                        const int* __restrict__ cnt, const float* __restrict__ h2,
                        float* __restrict__ out, int n) {
    int i = blockIdx.x * blockDim.x + threadIdx.x;
    if (i >= n) return;
    int beg = off[i];
    int end = beg + cnt[i];
    float s = 0.f;
#pragma unroll 4
    for (int j = beg; j < end; j++) {
        float2 p = pairs[j];
        s += p.y * h2[__float_as_int(p.x)];
    }
    out[i] += s;
}

extern "C" void kernel_launch(void* const* d_in, const int* in_sizes, int n_in,
                              void* d_out, int out_size, void* d_ws, size_t ws_size,
                              hipStream_t stream) {
    const float* x   = (const float*)d_in[0];
    const int*   idx = (const int*)d_in[1];      // int32 per harness contract
    const float* ew  = (const float*)d_in[2];
    const float* W1  = (const float*)d_in[3];
    const float* b1  = (const float*)d_in[4];
    const float* W2  = (const float*)d_in[5];
    const float* b2  = (const float*)d_in[6];
    float* out = (float*)d_out;

    const int N = N_NODES;
    const int E = N_EDGES;

    // ws layout (float units):
    // off[N] | cnt[N] | dinv[N] | boff[392] | btot[391] | pad ->
    // region A @300784 (3.4M floats): { hist[391*512]=200192 ints, bin[2E] }
    //                                  overlaid later by h1[64N fp16]      |
    // pairs[2E] @3700976 | h2[N] @6900976
    // total = 7,000,976 floats = 28.0 MB
    float* ws = (float*)d_ws;
    int*    off  = (int*)ws;
    int*    cnt  = (int*)(ws + (size_t)N);
    float*  dinv = ws + 2 * (size_t)N;
    int*    boff = (int*)(ws + 3 * (size_t)N);              // 392 ints
    int*    btot = (int*)(ws + 3 * (size_t)N + 392);        // 391 ints
    int*    hist = (int*)(ws + 300784);                      // 200192 ints
    float2* bin  = (float2*)(ws + 300784 + 200192);          // 2E floats, 8B aligned
    _Float16* h1 = (_Float16*)(ws + 300784);                 // overlays hist+bin
    float2* pairs = (float2*)(ws + 3700976);                 // 2E floats
    float*  h2   = ws + 6900976;

    p1_hist<<<NB1, 256, 0, stream>>>(idx, hist);
    p2a_scan<<<NBUCK, NB1, 0, stream>>>(hist, btot);
    p2b_scan<<<1, 512, 0, stream>>>(btot, boff);
    p3_part<<<NB1, 256, 0, stream>>>(idx, ew, hist, boff, bin);
    p4a_count<<<NBUCK, 512, 0, stream>>>(bin, boff, cnt, off, dinv);
    p4b_place<<<NBUCK, 512, 0, stream>>>(bin, boff, off, dinv, pairs);
    gemm1<<<(N + 63) / 64, 256, 0, stream>>>(x, W1, h1);   // h1 overlays hist+bin
    gather1<<<(N + 1) / 2, 128, 0, stream>>>((const half2v*)h1, pairs, off, cnt, dinv,
                                             b1, W2, b2, h2, out, N);
    gather2<<<(N + 255) / 256, 256, 0, stream>>>(pairs, off, cnt, h2, out, N);
}

// Round 6
// 226.287 us; speedup vs baseline: 1.4092x; 1.0091x over previous
//
#include <hip/hip_runtime.h>

// 2-layer GCN, N=100000, E=1600000, 64 -> 64 -> 1, f32.
//
// Round-10. r9 post-mortem: gather1 pinned at ~63us by random-128B L2-fill
// rate (164MB, MLP-insensitive) -- structural for now. Attack the ~165us in
// the other kernels:
//  - gemm1 had a 4-way LDS bank conflict on every x read (addr%32==k%32) and
//    ~75K LDS cycles/CU => ~30us. Rewrite: 128 rows/block, 8x8 out/thread,
//    padded xs[128][68], b128-only reads => ~19K cycles/CU.
//  - p4a+p4b fused (p4): pairs=(r, w*dinv[c]) uses own-bucket dinv only;
//    h1 pre-scaled by dinv[r] in gemm1; h2 pre-scaled by dinv[dst] in
//    gather1. Same math, kills the 12.8MB bin re-read + 1.6M dinv gathers.
//  - p2b eliminated (p3/p4 self-scan btot in LDS); cnt[] dropped (off[N]=E
//    sentinel); gather2 uses 4 lanes/dst + quad reduce.
//
// Pipeline (7 kernels, zero global atomics):
//   P1  hist : 512 blocks x 3125 edges; LDS hist over 391 buckets (dst>>8)
//   P2a scan : per bucket, exclusive scan over 512 block counts (+btot)
//   P3  part : self-scan btot->base; LDS rank; bin=(src|cl<<17, w)
//   P4  build: per bucket: packed u64 cnt/wsum -> off/dinv (+scan), then
//              rank+place pairs[off[c]+rank] = (src, w*dinv[c])
//   gemm1    : h1 = fp16(dinv[r] * (x @ W1))  [h1 overlays dead hist+bin]
//   gather1  : per-dst wave split-half dword gather; t=sum q*h1s; relu+b1;
//              h2s[dst]=di*(v.W2); out=b2+di*h2s
//   gather2  : 4 lanes/dst: out[dst] += sum q*h2s[src]

#define N_NODES 100000
#define N_EDGES 1600000
#define CNT_SHIFT 42
#define SUM_MASK ((1ull << CNT_SHIFT) - 1)
#define BSZ 256               // nodes per bucket
#define NBUCK 391             // ceil(100000 / 256)
#define NB1 512               // partition blocks
#define EPB 3125              // edges per partition block = E / NB1

typedef _Float16 half2v __attribute__((ext_vector_type(2)));

// P1: per-block LDS histogram over dst buckets.
__global__ void p1_hist(const int* __restrict__ idx, int* __restrict__ hist) {
    __shared__ int h[NBUCK];
    int t = threadIdx.x, blk = blockIdx.x;
    for (int i = t; i < NBUCK; i += 256) h[i] = 0;
    __syncthreads();
    int e0 = blk * EPB;
    for (int i = t; i < EPB; i += 256) {
        int c = idx[N_EDGES + e0 + i];
        atomicAdd(&h[c >> 8], 1);
    }
    __syncthreads();
    for (int i = t; i < NBUCK; i += 256) hist[(size_t)i * NB1 + blk] = h[i];
}

// P2a: per bucket, exclusive scan of its 512 per-block counts; total -> btot.
__global__ void p2a_scan(int* __restrict__ hist, int* __restrict__ btot) {
    __shared__ int s[NB1];
    int t = threadIdx.x, b = blockIdx.x;
    int v = hist[(size_t)b * NB1 + t];
    s[t] = v;
    __syncthreads();
#pragma unroll
    for (int d = 1; d < NB1; d <<= 1) {
        int u = (t >= d) ? s[t - d] : 0;
        __syncthreads();
        s[t] += u;
        __syncthreads();
    }
    hist[(size_t)b * NB1 + t] = s[t] - v;
    if (t == NB1 - 1) btot[b] = s[NB1 - 1];
}

// P3: partition edges into bucket segments. Self-scans btot for bucket bases.
__global__ void p3_part(const int* __restrict__ idx, const float* __restrict__ w,
                        const int* __restrict__ hist, const int* __restrict__ btot,
                        float2* __restrict__ bin) {
    __shared__ int sc[512];
    __shared__ int base[NBUCK];
    __shared__ int h[NBUCK];
    int t = threadIdx.x, blk = blockIdx.x;
    int v = (t < NBUCK) ? btot[t] : 0;
    sc[t] = v;
    __syncthreads();
#pragma unroll
    for (int d = 1; d < 512; d <<= 1) {
        int u = (t >= d) ? sc[t - d] : 0;
        __syncthreads();
        sc[t] += u;
        __syncthreads();
    }
    if (t < NBUCK) {
        base[t] = sc[t] - v + hist[(size_t)t * NB1 + blk];  // boff[t] + block base
        h[t] = 0;
    }
    __syncthreads();
    int e0 = blk * EPB;
    for (int i = t; i < EPB; i += 512) {
        int e = e0 + i;
        int r = idx[e];
        int c = idx[N_EDGES + e];
        int b = c >> 8;
        int lr = atomicAdd(&h[b], 1);
        bin[base[b] + lr] = make_float2(__int_as_float(r | ((c & 255) << 17)), w[e]);
    }
}

// P4 (fused count+place): per bucket. Pass A: packed u64 per-node cnt/wsum ->
// off/dinv (+node scan, sentinel off[N]=E). Pass B: LDS rank, write
// pairs[off[c]+rank] = (src, w*dinv[c]) -- own-bucket dinv only.
__global__ void p4_build(const float2* __restrict__ bin, const int* __restrict__ btot,
                         int* __restrict__ off, float* __restrict__ dinv,
                         float2* __restrict__ pairs) {
    __shared__ int sc[512];
    __shared__ unsigned long long pk[BSZ];
    __shared__ float dl[BSZ];
    __shared__ int ofl[BSZ];
    __shared__ int rk[BSZ];
    int t = threadIdx.x, b = blockIdx.x;
    int v = (t < NBUCK) ? btot[t] : 0;
    sc[t] = v;
    if (t < BSZ) { pk[t] = 0ull; rk[t] = 0; }
    __syncthreads();
#pragma unroll
    for (int d = 1; d < 512; d <<= 1) {
        int u = (t >= d) ? sc[t - d] : 0;
        __syncthreads();
        sc[t] += u;
        __syncthreads();
    }
    int s0 = (b > 0) ? sc[b - 1] : 0;   // inclusive-scan -> segment bounds
    int s1 = sc[b];
    // pass A: per-node count + weight-sum
    for (int j = s0 + t; j < s1; j += 512) {
        float2 p = bin[j];
        int cl = (__float_as_int(p.x) >> 17) & 255;
        // w in [0,1): w * 2^32 exact scale; per-node sum < cnt*2^32 < 2^42.
        unsigned long long add =
            (1ull << CNT_SHIFT) | (unsigned long long)(p.y * 4294967296.0f);
        atomicAdd(&pk[cl], add);
    }
    __syncthreads();
    unsigned long long pv = 0;
    int c = 0;
    if (t < BSZ) {
        pv = pk[t];
        c = (int)(pv >> CNT_SHIFT);
        sc[t] = c;
    }
    __syncthreads();
#pragma unroll
    for (int d = 1; d < BSZ; d <<= 1) {
        int u = (t >= d && t < BSZ) ? sc[t - d] : 0;
        __syncthreads();
        if (t < BSZ) sc[t] += u;
        __syncthreads();
    }
    if (t < BSZ) {
        int o = s0 + sc[t] - c;
        ofl[t] = o;
        float deg = 1.0f + (float)(pv & SUM_MASK) * 2.3283064365386963e-10f;
        float di = rsqrtf(deg);
        dl[t] = di;
        int node = b * BSZ + t;
        if (node < N_NODES) { off[node] = o; dinv[node] = di; }
    }
    if (b == NBUCK - 1 && t == 0) off[N_NODES] = s1;   // sentinel = E
    __syncthreads();
    // pass B: rank + place (bin segment is L2-hot from pass A)
    for (int j = s0 + t; j < s1; j += 512) {
        float2 p = bin[j];
        int bits = __float_as_int(p.x);
        int r = bits & 0x1FFFF;
        int cl = (bits >> 17) & 255;
        int rank = atomicAdd(&rk[cl], 1);
        pairs[ofl[cl] + rank] = make_float2(__int_as_float(r), p.y * dl[cl]);
    }
}

// 128 rows/block, 128 threads; 8 rows x 8 cols per thread, b128-only LDS
// (xs padded [128][68] -> conflict-free). Epilogue: h1s = fp16(dinv * acc).
__global__ void gemm1(const float* __restrict__ x, const float* __restrict__ W1,
                      const float* __restrict__ dinv, _Float16* __restrict__ h1) {
    __shared__ float xs[128 * 68];
    __shared__ float w1s[64 * 64];
    int t = threadIdx.x;
    int row0 = blockIdx.x * 128;

    const float4* W4g = (const float4*)W1;
    float4* w1s4 = (float4*)w1s;
#pragma unroll
    for (int i = 0; i < 8; i++) w1s4[t + 128 * i] = W4g[t + 128 * i];
    const float4* X4 = (const float4*)x;
#pragma unroll
    for (int i = 0; i < 16; i++) {
        int fi = t + 128 * i;          // float4 index in 128x16 tile
        int rl = fi >> 4;
        int kq = fi & 15;
        int row = row0 + rl;
        float4 vv = (row < N_NODES) ? X4[(size_t)row * 16 + kq]
                                    : make_float4(0.f, 0.f, 0.f, 0.f);
        *(float4*)&xs[rl * 68 + kq * 4] = vv;
    }
    __syncthreads();

    int cq = t & 7;      // cols 8cq..8cq+7
    int rq = t >> 3;     // rows rq + 16i
    float acc[8][8];
#pragma unroll
    for (int i = 0; i < 8; i++)
#pragma unroll
        for (int j = 0; j < 8; j++) acc[i][j] = 0.f;

    for (int k = 0; k < 64; k += 4) {
        float4 xv[8];
#pragma unroll
        for (int i = 0; i < 8; i++)
            xv[i] = *(const float4*)&xs[(rq + 16 * i) * 68 + k];
        float4 wv[4][2];
#pragma unroll
        for (int kk = 0; kk < 4; kk++) {
            wv[kk][0] = w1s4[(k + kk) * 16 + 2 * cq];
            wv[kk][1] = w1s4[(k + kk) * 16 + 2 * cq + 1];
        }
#pragma unroll
        for (int i = 0; i < 8; i++) {
            float xk[4] = {xv[i].x, xv[i].y, xv[i].z, xv[i].w};
#pragma unroll
            for (int kk = 0; kk < 4; kk++) {
                acc[i][0] += xk[kk] * wv[kk][0].x;
                acc[i][1] += xk[kk] * wv[kk][0].y;
                acc[i][2] += xk[kk] * wv[kk][0].z;
                acc[i][3] += xk[kk] * wv[kk][0].w;
                acc[i][4] += xk[kk] * wv[kk][1].x;
                acc[i][5] += xk[kk] * wv[kk][1].y;
                acc[i][6] += xk[kk] * wv[kk][1].z;
                acc[i][7] += xk[kk] * wv[kk][1].w;
            }
        }
    }
#pragma unroll
    for (int i = 0; i < 8; i++) {
        int row = row0 + rq + 16 * i;
        if (row < N_NODES) {
            float di = dinv[row];
            half2v h4[4];
#pragma unroll
            for (int j = 0; j < 4; j++)
                h4[j] = half2v{(_Float16)(acc[i][2 * j] * di),
                               (_Float16)(acc[i][2 * j + 1] * di)};
            *(float4*)(h1 + (size_t)row * 64 + 8 * cq) = *(float4*)h4;
        }
    }
}

// One wave per dst. Rows gathered as 32 lanes x dword (2 fp16 ch/lane);
// halves process even/odd edges, 8 edges per half in flight. pairs.y is
// pre-scaled (w*dinv_c) and h1s pre-scaled (dinv_r): product = norm*h1.
__global__ void gather1(const half2v* __restrict__ h1v, const float2* __restrict__ pairs,
                        const int* __restrict__ off, const float* __restrict__ dinv,
                        const float* __restrict__ b1, const float* __restrict__ W2,
                        const float* __restrict__ b2, float* __restrict__ h2,
                        float* __restrict__ out, int n) {
    int t = threadIdx.x;
    int lane = t & 63;
    int half = lane >> 5;       // 0: even edges, 1: odd edges
    int cl = lane & 31;         // channel pair: handles ch 2*cl, 2*cl+1
    int dst = blockIdx.x * 2 + (t >> 6);
    if (dst >= n) return;
    int beg = off[dst];
    int end = off[dst + 1];
    float di = dinv[dst];
    float a0 = 0.f, a1 = 0.f, b0 = 0.f, b1a = 0.f;
    float c0 = 0.f, c1 = 0.f, d0 = 0.f, d1 = 0.f;
    int j = beg + half;
    for (; j + 14 < end; j += 16) {   // 8 edges per half per iter
        float2 p0 = pairs[j],      p1 = pairs[j + 2],  p2 = pairs[j + 4],  p3 = pairs[j + 6];
        float2 p4 = pairs[j + 8],  p5 = pairs[j + 10], p6 = pairs[j + 12], p7 = pairs[j + 14];
        half2v v0 = h1v[__float_as_int(p0.x) * 32 + cl];
        half2v v1 = h1v[__float_as_int(p1.x) * 32 + cl];
        half2v v2 = h1v[__float_as_int(p2.x) * 32 + cl];
        half2v v3 = h1v[__float_as_int(p3.x) * 32 + cl];
        half2v v4 = h1v[__float_as_int(p4.x) * 32 + cl];
        half2v v5 = h1v[__float_as_int(p5.x) * 32 + cl];
        half2v v6 = h1v[__float_as_int(p6.x) * 32 + cl];
        half2v v7 = h1v[__float_as_int(p7.x) * 32 + cl];
        a0 += p0.y * (float)v0[0]; a1 += p0.y * (float)v0[1];
        b0 += p1.y * (float)v1[0]; b1a += p1.y * (float)v1[1];
        c0 += p2.y * (float)v2[0]; c1 += p2.y * (float)v2[1];
        d0 += p3.y * (float)v3[0]; d1 += p3.y * (float)v3[1];
        a0 += p4.y * (float)v4[0]; a1 += p4.y * (float)v4[1];
        b0 += p5.y * (float)v5[0]; b1a += p5.y * (float)v5[1];
        c0 += p6.y * (float)v6[0]; c1 += p6.y * (float)v6[1];
        d0 += p7.y * (float)v7[0]; d1 += p7.y * (float)v7[1];
    }
    for (; j + 6 < end; j += 8) {     // 4 edges per half
        float2 p0 = pairs[j], p1 = pairs[j + 2], p2 = pairs[j + 4], p3 = pairs[j + 6];
        half2v v0 = h1v[__float_as_int(p0.x) * 32 + cl];
        half2v v1 = h1v[__float_as_int(p1.x) * 32 + cl];
        half2v v2 = h1v[__float_as_int(p2.x) * 32 + cl];
        half2v v3 = h1v[__float_as_int(p3.x) * 32 + cl];
        a0 += p0.y * (float)v0[0]; a1 += p0.y * (float)v0[1];
        b0 += p1.y * (float)v1[0]; b1a += p1.y * (float)v1[1];
        c0 += p2.y * (float)v2[0]; c1 += p2.y * (float)v2[1];
        d0 += p3.y * (float)v3[0]; d1 += p3.y * (float)v3[1];
    }
    for (; j < end; j += 2) {
        float2 p = pairs[j];
        half2v v = h1v[__float_as_int(p.x) * 32 + cl];
        a0 += p.y * (float)v[0]; a1 += p.y * (float)v[1];
    }
    float t0 = (a0 + b0) + (c0 + d0);
    float t1 = (a1 + b1a) + (c1 + d1);
    // merge even/odd halves (lanes l and l^32 hold same channels)
    t0 += __shfl_xor(t0, 32, 64);
    t1 += __shfl_xor(t1, 32, 64);
    // self-loop: di * h1s[dst] = dinv^2 * h1[dst]
    half2v sv = h1v[dst * 32 + cl];
    t0 += (float)sv[0] * di;
    t1 += (float)sv[1] * di;
    float2 b1p = ((const float2*)b1)[cl];
    float v0 = fmaxf(t0 + b1p.x, 0.0f);
    float v1 = fmaxf(t1 + b1p.y, 0.0f);
    float2 w2p = ((const float2*)W2)[cl];
    float p = v0 * w2p.x + v1 * w2p.y;
#pragma unroll
    for (int o = 16; o > 0; o >>= 1) p += __shfl_xor(p, o, 64);
    if (lane == 0) {
        h2[dst] = p * di;                 // pre-scaled h2s = dinv*h2
        out[dst] = b2[0] + p * di * di;   // bias + layer-2 self-loop
    }
}

// 4 lanes per dst: out[dst] += sum q * h2s[src], quad shuffle-reduce.
__global__ void gather2(const float2* __restrict__ pairs, const int* __restrict__ off,
                        const float* __restrict__ h2, float* __restrict__ out, int n) {
    int t = threadIdx.x;
    int i = blockIdx.x * 64 + (t >> 2);
    if (i >= n) return;
    int q = t & 3;
    int beg = off[i], end = off[i + 1];
    float s = 0.f;
    for (int j = beg + q; j < end; j += 4) {
        float2 p = pairs[j];
        s += p.y * h2[__float_as_int(p.x)];
    }
    s += __shfl_xor(s, 1, 64);
    s += __shfl_xor(s, 2, 64);
    if (q == 0) out[i] += s;
}

extern "C" void kernel_launch(void* const* d_in, const int* in_sizes, int n_in,
                              void* d_out, int out_size, void* d_ws, size_t ws_size,
                              hipStream_t stream) {
    const float* x   = (const float*)d_in[0];
    const int*   idx = (const int*)d_in[1];      // int32 per harness contract
    const float* ew  = (const float*)d_in[2];
    const float* W1  = (const float*)d_in[3];
    const float* b1  = (const float*)d_in[4];
    const float* W2  = (const float*)d_in[5];
    const float* b2  = (const float*)d_in[6];
    float* out = (float*)d_out;

    const int N = N_NODES;

    // ws layout (float units):
    // off[N+1] @0 | dinv[N] @100004 | btot[391] @200004 |
    // region A @200400: { hist[NB1*NBUCK=200192] , bin[2E=3.2M] }
    //                    overlaid later by h1[64N fp16 = 3.2M floats]
    // pairs[2E] @3600592 | h2[N] @6800592
    // total = 6,900,592 floats = 27.6 MB
    float* ws = (float*)d_ws;
    int*    off  = (int*)ws;                                 // N+1
    float*  dinv = ws + 100004;
    int*    btot = (int*)(ws + 200004);                      // 391
    int*    hist = (int*)(ws + 200400);                      // 200192 ints
    float2* bin  = (float2*)(ws + 200400 + 200192);          // 2E floats
    _Float16* h1 = (_Float16*)(ws + 200400);                 // overlays hist+bin
    float2* pairs = (float2*)(ws + 3600592);                 // 2E floats
    float*  h2   = ws + 6800592;

    p1_hist<<<NB1, 256, 0, stream>>>(idx, hist);
    p2a_scan<<<NBUCK, NB1, 0, stream>>>(hist, btot);
    p3_part<<<NB1, 512, 0, stream>>>(idx, ew, hist, btot, bin);
    p4_build<<<NBUCK, 512, 0, stream>>>(bin, btot, off, dinv, pairs);
    gemm1<<<(N + 127) / 128, 128, 0, stream>>>(x, W1, dinv, h1);  // h1 overlays bin
    gather1<<<(N + 1) / 2, 128, 0, stream>>>((const half2v*)h1, pairs, off, dinv,
                                             b1, W2, b2, h2, out, N);
    gather2<<<(N + 63) / 64, 256, 0, stream>>>(pairs, off, h2, out, N);
}